// Round 10
// baseline (1122.851 us; speedup 1.0000x reference)
//
#include <hip/hip_runtime.h>

#define BATCH 8
#define NN 10000      // nodes per graph (N)
#define STB 1024      // block size (16 waves)

typedef _Float16 h2 __attribute__((ext_vector_type(2)));

// Packed 2xf16 LDS atomic add (ds_pk_add_f16): one atomic covers TWO batches.
__device__ __forceinline__ void lds_pk_add(h2* p, h2 v) {
    __builtin_amdgcn_ds_atomic_fadd_v2f16(
        (__attribute__((address_space(3))) h2*)p, v);
}

// Device-scope spin barrier. Safe by capacity arithmetic: grid = 512 blocks
// x 1024 thr x 80384 B LDS = exactly 2 blocks/CU x 256 CU co-resident
// (160768 <= 163840 LDS, 32/32 waves, VGPR <= 64 via launch_bounds).
__device__ __forceinline__ void gbar(int* ctr, int target) {
    __syncthreads();
    __threadfence();                        // release this block's writes
    if (threadIdx.x == 0) {
        __hip_atomic_fetch_add(ctr, 1, __ATOMIC_ACQ_REL, __HIP_MEMORY_SCOPE_AGENT);
        while (__hip_atomic_load(ctr, __ATOMIC_ACQUIRE, __HIP_MEMORY_SCOPE_AGENT) < target)
            __builtin_amdgcn_s_sleep(8);
    }
    __syncthreads();
    __threadfence();                        // acquire other blocks' writes
}

// One dispatch: S1 scatter -> R1 (pred,err,err2) -> S2 scatter -> R2 (dx).
// block: k = bid>>2 (edge chunk), bp = bid&3 (batch pair).
__global__ __launch_bounds__(STB, 8) void pc_fused(
        const float* __restrict__ values,   // [8*N]
        const float* __restrict__ w,        // [E]
        const int* __restrict__ idx,        // [2,E]
        float* __restrict__ pred, float* __restrict__ err,
        float* __restrict__ dx,
        h2* __restrict__ err2,              // [4*N]
        h2* __restrict__ partial,           // [K*4][N]
        int* __restrict__ ctr,
        int E, int N, int chunk, int K)
{
    __shared__ alignas(16) h2 acc2[NN];
    __shared__ alignas(16) h2 stage[NN];

    const int bid = blockIdx.x, nb = gridDim.x;
    const int k = bid >> 2, bp = bid & 3;
    const int tid = threadIdx.x;
    const int n4 = N >> 2;                 // N % 4 == 0

    long e0 = (long)k * chunk, e1 = e0 + chunk;
    if (e0 > E) e0 = E;
    if (e1 > E) e1 = E;
    const long n = e1 - e0, nv = n >> 2;

    // ======== S1: scatter w * tanh(values) by tgt into LDS, flush ========
    {
        const float* __restrict__ v0 = values + (long)(2 * bp) * N;
        const float* __restrict__ v1 = v0 + N;
        int4* az = (int4*)acc2;
        for (int i = tid; i < n4; i += STB) az[i] = make_int4(0, 0, 0, 0);
        for (int i = tid; i < N; i += STB) {
            h2 f = { (_Float16)tanhf(v0[i]), (_Float16)tanhf(v1[i]) };
            stage[i] = f;
        }
        __syncthreads();

        const int4*   g4p = (const int4*)(idx + e0);           // src: gather
        const int4*   s4p = (const int4*)(idx + (long)E + e0); // tgt: scatter
        const float4* w4p = (const float4*)(w + e0);
        for (long v = tid; v < nv; v += STB) {
            int4 gi = g4p[v]; int4 si = s4p[v]; float4 wv = w4p[v];
            h2 w0 = { (_Float16)wv.x, (_Float16)wv.x };
            h2 w1 = { (_Float16)wv.y, (_Float16)wv.y };
            h2 w2 = { (_Float16)wv.z, (_Float16)wv.z };
            h2 w3 = { (_Float16)wv.w, (_Float16)wv.w };
            h2 m0 = w0 * stage[gi.x];
            h2 m1 = w1 * stage[gi.y];
            h2 m2 = w2 * stage[gi.z];
            h2 m3 = w3 * stage[gi.w];
            lds_pk_add(&acc2[si.x], m0);
            lds_pk_add(&acc2[si.y], m1);
            lds_pk_add(&acc2[si.z], m2);
            lds_pk_add(&acc2[si.w], m3);
        }
        for (long e = (nv << 2) + tid; e < n; e += STB) {
            int gi = idx[e0 + e], si = idx[(long)E + e0 + e];
            _Float16 wf = (_Float16)w[e0 + e];
            h2 wb = { wf, wf };
            lds_pk_add(&acc2[si], wb * stage[gi]);
        }
        __syncthreads();
        int4* pz = (int4*)(partial + (long)bid * N);
        for (int i = tid; i < n4; i += STB) pz[i] = az[i];
    }
    gbar(ctr, nb);

    // ======== R1: pred = sum_k partial; err = values - pred; err2 ========
    for (int c = bid * STB + tid; c < 4 * N; c += nb * STB) {
        int bpc = c / N, t = c - bpc * N;
        const h2* p = partial + (long)bpc * N + t;
        const long stride = (long)4 * N;
        float2 a0 = {0.f,0.f}, a1 = {0.f,0.f}, a2 = {0.f,0.f}, a3 = {0.f,0.f};
        int kk = 0;
        for (; kk + 4 <= K; kk += 4) {
            h2 q0 = p[(kk + 0) * stride];
            h2 q1 = p[(kk + 1) * stride];
            h2 q2 = p[(kk + 2) * stride];
            h2 q3 = p[(kk + 3) * stride];
            a0.x += (float)q0.x; a0.y += (float)q0.y;
            a1.x += (float)q1.x; a1.y += (float)q1.y;
            a2.x += (float)q2.x; a2.y += (float)q2.y;
            a3.x += (float)q3.x; a3.y += (float)q3.y;
        }
        for (; kk < K; ++kk) {
            h2 q = p[kk * stride];
            a0.x += (float)q.x; a0.y += (float)q.y;
        }
        float sx = (a0.x + a1.x) + (a2.x + a3.x);
        float sy = (a0.y + a1.y) + (a2.y + a3.y);
        long j0 = (long)(2 * bpc) * N + t, j1 = j0 + N;
        float ea = values[j0] - sx, eb = values[j1] - sy;
        pred[j0] = sx; pred[j1] = sy;
        err[j0] = ea;  err[j1] = eb;
        h2 ep = { (_Float16)ea, (_Float16)eb };
        err2[c] = ep;
    }
    gbar(ctr, 2 * nb);

    // ======== S2: scatter w * err by src into LDS, flush ========
    {
        int4* az = (int4*)acc2;
        int4* ez = (int4*)stage;
        const int4* e4 = (const int4*)(err2 + (long)bp * N);
        for (int i = tid; i < n4; i += STB) {
            az[i] = make_int4(0, 0, 0, 0);
            ez[i] = e4[i];
        }
        __syncthreads();

        const int4*   g4p = (const int4*)(idx + (long)E + e0); // tgt: gather
        const int4*   s4p = (const int4*)(idx + e0);           // src: scatter
        const float4* w4p = (const float4*)(w + e0);
        for (long v = tid; v < nv; v += STB) {
            int4 gi = g4p[v]; int4 si = s4p[v]; float4 wv = w4p[v];
            h2 w0 = { (_Float16)wv.x, (_Float16)wv.x };
            h2 w1 = { (_Float16)wv.y, (_Float16)wv.y };
            h2 w2 = { (_Float16)wv.z, (_Float16)wv.z };
            h2 w3 = { (_Float16)wv.w, (_Float16)wv.w };
            h2 m0 = w0 * stage[gi.x];
            h2 m1 = w1 * stage[gi.y];
            h2 m2 = w2 * stage[gi.z];
            h2 m3 = w3 * stage[gi.w];
            lds_pk_add(&acc2[si.x], m0);
            lds_pk_add(&acc2[si.y], m1);
            lds_pk_add(&acc2[si.z], m2);
            lds_pk_add(&acc2[si.w], m3);
        }
        for (long e = (nv << 2) + tid; e < n; e += STB) {
            int gi = idx[(long)E + e0 + e], si = idx[e0 + e];
            _Float16 wf = (_Float16)w[e0 + e];
            h2 wb = { wf, wf };
            lds_pk_add(&acc2[si], wb * stage[gi]);
        }
        __syncthreads();
        int4* pz = (int4*)(partial + (long)bid * N);
        for (int i = tid; i < n4; i += STB) pz[i] = az[i];
    }
    gbar(ctr, 3 * nb);

    // ======== R2: dx = err - (1 - tanh^2(x)) * aggr ========
    for (int c = bid * STB + tid; c < 4 * N; c += nb * STB) {
        int bpc = c / N, t = c - bpc * N;
        const h2* p = partial + (long)bpc * N + t;
        const long stride = (long)4 * N;
        float2 a0 = {0.f,0.f}, a1 = {0.f,0.f}, a2 = {0.f,0.f}, a3 = {0.f,0.f};
        int kk = 0;
        for (; kk + 4 <= K; kk += 4) {
            h2 q0 = p[(kk + 0) * stride];
            h2 q1 = p[(kk + 1) * stride];
            h2 q2 = p[(kk + 2) * stride];
            h2 q3 = p[(kk + 3) * stride];
            a0.x += (float)q0.x; a0.y += (float)q0.y;
            a1.x += (float)q1.x; a1.y += (float)q1.y;
            a2.x += (float)q2.x; a2.y += (float)q2.y;
            a3.x += (float)q3.x; a3.y += (float)q3.y;
        }
        for (; kk < K; ++kk) {
            h2 q = p[kk * stride];
            a0.x += (float)q.x; a0.y += (float)q.y;
        }
        float sx = (a0.x + a1.x) + (a2.x + a3.x);
        float sy = (a0.y + a1.y) + (a2.y + a3.y);
        long j0 = (long)(2 * bpc) * N + t, j1 = j0 + N;
        float f0 = tanhf(values[j0]), f1 = tanhf(values[j1]);
        dx[j0] = err[j0] - (1.0f - f0 * f0) * sx;
        dx[j1] = err[j1] - (1.0f - f1 * f1) * sy;
    }
}

extern "C" void kernel_launch(void* const* d_in, const int* in_sizes, int n_in,
                              void* d_out, int out_size, void* d_ws, size_t ws_size,
                              hipStream_t stream) {
    const float* values  = (const float*)d_in[0];   // [B*N]
    const float* weights = (const float*)d_in[1];   // [E]
    const int*   edge_ix = (const int*)d_in[2];     // [2, E]

    const int BN = in_sizes[0];        // 80000
    int E  = in_sizes[1];              // 2,000,000
    int N  = BN / BATCH;               // 10000

    float* out  = (float*)d_out;       // [3, B*N]
    float* pred = out;
    float* err  = out + BN;
    float* dx   = out + 2 * BN;

    // workspace: ctr (16B slot) | err2 [4*N] h2 | partial [K*4][N] h2
    auto align16 = [](size_t x) { return (x + 15) & ~(size_t)15; };
    char* ws = (char*)d_ws;
    int* ctr = (int*)ws;
    size_t off = 16;
    h2* err2 = (h2*)(ws + off);
    off += align16((size_t)4 * N * sizeof(h2));
    int K = 128;
    while (K > 16 && off + (size_t)K * 4 * N * sizeof(h2) > ws_size) K >>= 1;
    h2* partial = (h2*)(ws + off);

    int chunk = (((E + K - 1) / K) + 3) & ~3;
    int Kused = (E + chunk - 1) / chunk;
    int grid  = Kused * 4;             // 512 @ K=128 -> exactly 2 blocks/CU

    hipMemsetAsync(ctr, 0, sizeof(int), stream);
    pc_fused<<<dim3(grid), dim3(STB), 0, stream>>>(
        values, weights, edge_ix, pred, err, dx, err2, partial, ctr,
        E, N, chunk, Kused);
}

// Round 11
// 177.394 us; speedup vs baseline: 6.3297x; 6.3297x over previous
//
#include <hip/hip_runtime.h>

#define BATCH 8
#define NN 10000      // nodes per graph (N)
#define STB 1024      // scatter block size (16 waves)

typedef _Float16 h2 __attribute__((ext_vector_type(2)));

// Packed 2xf16 LDS atomic add (ds_pk_add_f16): one atomic covers TWO batches.
__device__ __forceinline__ void lds_pk_add(h2* p, h2 v) {
    __builtin_amdgcn_ds_atomic_fadd_v2f16(
        (__attribute__((address_space(3))) h2*)p, v);
}

// prep: fx2[bp*N + t] = { tanh(values[2bp*N+t]), tanh(values[(2bp+1)*N+t]) }
__global__ __launch_bounds__(256) void prep_kernel(
        const float* __restrict__ values, h2* __restrict__ fx2, int N)
{
    int i = blockIdx.x * 256 + threadIdx.x;
    if (i >= 4 * N) return;
    int bp = i / N, t = i - bp * N;
    float a = values[(long)(2 * bp) * N + t];
    float b = values[(long)(2 * bp + 1) * N + t];
    h2 f = { (_Float16)tanhf(a), (_Float16)tanhf(b) };
    fx2[i] = f;
}

// Scatter: block (chunk k, batch-pair bp). Gather g2[bp*N + gi] (4B global,
// L1/L2-resident, VMEM pipe) and pk-atomic into h2 LDS accumulator (DS pipe
// carries ONLY atomics). partial[(k*4+bp)*N + t] (h2).
// goff/soff select gather/scatter rows of edge_index.
__global__ __launch_bounds__(STB, 8) void scatter_kernel(
        const h2* __restrict__ g2,       // [4*N] packed gather values
        const float* __restrict__ w,     // [E]
        const int* __restrict__ idx,     // [2,E]
        h2* __restrict__ partial,
        int E, int N, int chunk, long goff, long soff)
{
    __shared__ alignas(16) h2 acc2[NN];
    const int k = blockIdx.x, bp = blockIdx.y;
    const h2* __restrict__ gb = g2 + (long)bp * N;

    int n4 = N >> 2;                       // N % 4 == 0
    int4* az = (int4*)acc2;
    for (int i = threadIdx.x; i < n4; i += STB) az[i] = make_int4(0, 0, 0, 0);
    __syncthreads();

    long e0 = (long)k * chunk, e1 = e0 + chunk;
    if (e1 > E) e1 = E;
    long n = e1 - e0, nv = n >> 2;
    const int4*   g4p = (const int4*)(idx + goff + e0);
    const int4*   s4p = (const int4*)(idx + soff + e0);
    const float4* w4p = (const float4*)(w + e0);

    for (long v = threadIdx.x; v < nv; v += STB) {
        int4 gi = g4p[v]; int4 si = s4p[v]; float4 wv = w4p[v];
        // 4 independent VMEM gathers (L1/L2-resident), then 4 DS atomics
        h2 f0 = gb[gi.x];
        h2 f1 = gb[gi.y];
        h2 f2 = gb[gi.z];
        h2 f3 = gb[gi.w];
        h2 w0 = { (_Float16)wv.x, (_Float16)wv.x };
        h2 w1 = { (_Float16)wv.y, (_Float16)wv.y };
        h2 w2 = { (_Float16)wv.z, (_Float16)wv.z };
        h2 w3 = { (_Float16)wv.w, (_Float16)wv.w };
        lds_pk_add(&acc2[si.x], w0 * f0);
        lds_pk_add(&acc2[si.y], w1 * f1);
        lds_pk_add(&acc2[si.z], w2 * f2);
        lds_pk_add(&acc2[si.w], w3 * f3);
    }
    for (long e = (nv << 2) + threadIdx.x; e < n; e += STB) {
        int gi = idx[goff + e0 + e], si = idx[soff + e0 + e];
        _Float16 wf = (_Float16)w[e0 + e];
        h2 wb = { wf, wf };
        lds_pk_add(&acc2[si], wb * gb[gi]);
    }
    __syncthreads();

    int4* pz = (int4*)(partial + ((long)k * 4 + bp) * N);
    for (int i = threadIdx.x; i < n4; i += STB) pz[i] = az[i];
}

// ---------------- reduce 1: pred, err, err2 ----------------
// 512 thr: 64 lanes (4 consecutive t via int4) x 8 k-groups; fp32 tree.
__global__ __launch_bounds__(512) void reduce1_kernel(
        const h2* __restrict__ partial,
        const float* __restrict__ values,
        float* __restrict__ pred, float* __restrict__ err,
        h2* __restrict__ err2, int N, int K)
{
    __shared__ float2 sm[8][64][4];
    const int l = threadIdx.x & 63, g = threadIdx.x >> 6;
    const int bp = blockIdx.y;
    const int t = blockIdx.x * 256 + l * 4;
    float2 a0 = {0.f,0.f}, a1 = {0.f,0.f}, a2 = {0.f,0.f}, a3 = {0.f,0.f};
    const bool ok = (t + 3) < N;
    if (ok) {
        for (int kk = g; kk < K; kk += 8) {
            int4 v = *(const int4*)(partial + (long)(kk * 4 + bp) * N + t);
            h2* hp = (h2*)&v;
            a0.x += (float)hp[0].x; a0.y += (float)hp[0].y;
            a1.x += (float)hp[1].x; a1.y += (float)hp[1].y;
            a2.x += (float)hp[2].x; a2.y += (float)hp[2].y;
            a3.x += (float)hp[3].x; a3.y += (float)hp[3].y;
        }
    }
    sm[g][l][0] = a0; sm[g][l][1] = a1; sm[g][l][2] = a2; sm[g][l][3] = a3;
    __syncthreads();
    if (g == 0 && ok) {
#pragma unroll
        for (int r = 1; r < 8; ++r) {
            a0.x += sm[r][l][0].x; a0.y += sm[r][l][0].y;
            a1.x += sm[r][l][1].x; a1.y += sm[r][l][1].y;
            a2.x += sm[r][l][2].x; a2.y += sm[r][l][2].y;
            a3.x += sm[r][l][3].x; a3.y += sm[r][l][3].y;
        }
        long j0 = (long)(2 * bp) * N + t, j1 = j0 + N;
        float4 p0 = { a0.x, a1.x, a2.x, a3.x };
        float4 p1 = { a0.y, a1.y, a2.y, a3.y };
        float4 v0 = *(const float4*)(values + j0);
        float4 v1 = *(const float4*)(values + j1);
        float4 e0 = { v0.x - p0.x, v0.y - p0.y, v0.z - p0.z, v0.w - p0.w };
        float4 e1 = { v1.x - p1.x, v1.y - p1.y, v1.z - p1.z, v1.w - p1.w };
        *(float4*)(pred + j0) = p0;
        *(float4*)(pred + j1) = p1;
        *(float4*)(err + j0) = e0;
        *(float4*)(err + j1) = e1;
        h2 pk[4] = { { (_Float16)e0.x, (_Float16)e1.x },
                     { (_Float16)e0.y, (_Float16)e1.y },
                     { (_Float16)e0.z, (_Float16)e1.z },
                     { (_Float16)e0.w, (_Float16)e1.w } };
        *(int4*)(err2 + (long)bp * N + t) = *(int4*)pk;
    }
}

// ---------------- reduce 2: dx = err - (1 - tanh^2(x)) * aggr ----------------
__global__ __launch_bounds__(512) void reduce2_kernel(
        const h2* __restrict__ partial,
        const float* __restrict__ values,
        const float* __restrict__ err,
        float* __restrict__ dx, int N, int K)
{
    __shared__ float2 sm[8][64][4];
    const int l = threadIdx.x & 63, g = threadIdx.x >> 6;
    const int bp = blockIdx.y;
    const int t = blockIdx.x * 256 + l * 4;
    float2 a0 = {0.f,0.f}, a1 = {0.f,0.f}, a2 = {0.f,0.f}, a3 = {0.f,0.f};
    const bool ok = (t + 3) < N;
    if (ok) {
        for (int kk = g; kk < K; kk += 8) {
            int4 v = *(const int4*)(partial + (long)(kk * 4 + bp) * N + t);
            h2* hp = (h2*)&v;
            a0.x += (float)hp[0].x; a0.y += (float)hp[0].y;
            a1.x += (float)hp[1].x; a1.y += (float)hp[1].y;
            a2.x += (float)hp[2].x; a2.y += (float)hp[2].y;
            a3.x += (float)hp[3].x; a3.y += (float)hp[3].y;
        }
    }
    sm[g][l][0] = a0; sm[g][l][1] = a1; sm[g][l][2] = a2; sm[g][l][3] = a3;
    __syncthreads();
    if (g == 0 && ok) {
#pragma unroll
        for (int r = 1; r < 8; ++r) {
            a0.x += sm[r][l][0].x; a0.y += sm[r][l][0].y;
            a1.x += sm[r][l][1].x; a1.y += sm[r][l][1].y;
            a2.x += sm[r][l][2].x; a2.y += sm[r][l][2].y;
            a3.x += sm[r][l][3].x; a3.y += sm[r][l][3].y;
        }
        long j0 = (long)(2 * bp) * N + t, j1 = j0 + N;
        float4 g0 = { a0.x, a1.x, a2.x, a3.x };
        float4 g1 = { a0.y, a1.y, a2.y, a3.y };
        float4 v0 = *(const float4*)(values + j0);
        float4 v1 = *(const float4*)(values + j1);
        float4 e0 = *(const float4*)(err + j0);
        float4 e1 = *(const float4*)(err + j1);
        float4 d0, d1;
        float f;
        f = tanhf(v0.x); d0.x = e0.x - (1.0f - f * f) * g0.x;
        f = tanhf(v0.y); d0.y = e0.y - (1.0f - f * f) * g0.y;
        f = tanhf(v0.z); d0.z = e0.z - (1.0f - f * f) * g0.z;
        f = tanhf(v0.w); d0.w = e0.w - (1.0f - f * f) * g0.w;
        f = tanhf(v1.x); d1.x = e1.x - (1.0f - f * f) * g1.x;
        f = tanhf(v1.y); d1.y = e1.y - (1.0f - f * f) * g1.y;
        f = tanhf(v1.z); d1.z = e1.z - (1.0f - f * f) * g1.z;
        f = tanhf(v1.w); d1.w = e1.w - (1.0f - f * f) * g1.w;
        *(float4*)(dx + j0) = d0;
        *(float4*)(dx + j1) = d1;
    }
}

extern "C" void kernel_launch(void* const* d_in, const int* in_sizes, int n_in,
                              void* d_out, int out_size, void* d_ws, size_t ws_size,
                              hipStream_t stream) {
    const float* values  = (const float*)d_in[0];   // [B*N]
    const float* weights = (const float*)d_in[1];   // [E]
    const int*   edge_ix = (const int*)d_in[2];     // [2, E]

    const int BN = in_sizes[0];        // 80000
    const int E  = in_sizes[1];        // 2,000,000
    const int N  = BN / BATCH;         // 10000

    float* out  = (float*)d_out;       // [3, B*N]
    float* pred = out;
    float* err  = out + BN;
    float* dx   = out + 2 * BN;

    // workspace: fx2 [4N] h2 | err2 [4N] h2 | partial [K*4][N] h2
    auto align16 = [](size_t x) { return (x + 15) & ~(size_t)15; };
    char* ws = (char*)d_ws;
    h2* fx2 = (h2*)ws;
    size_t off = align16((size_t)4 * N * sizeof(h2));
    h2* err2 = (h2*)(ws + off);
    off += align16((size_t)4 * N * sizeof(h2));
    int K = 128;
    while (K > 16 && off + (size_t)K * 4 * N * sizeof(h2) > ws_size) K >>= 1;
    h2* partial = (h2*)(ws + off);

    int chunk = (((E + K - 1) / K) + 3) & ~3;
    int Kused = (E + chunk - 1) / chunk;

    dim3 sgrid(Kused, 4);                 // 4 batch-pairs
    dim3 rgrid((N + 255) / 256, 4);       // 512-thread reduce blocks

    prep_kernel<<<(4 * N + 255) / 256, 256, 0, stream>>>(values, fx2, N);
    scatter_kernel<<<sgrid, STB, 0, stream>>>(fx2, weights, edge_ix, partial,
                                              E, N, chunk, 0L, (long)E);
    reduce1_kernel<<<rgrid, 512, 0, stream>>>(partial, values, pred, err,
                                              err2, N, Kused);
    scatter_kernel<<<sgrid, STB, 0, stream>>>(err2, weights, edge_ix, partial,
                                              E, N, chunk, (long)E, 0L);
    reduce2_kernel<<<rgrid, 512, 0, stream>>>(partial, values, err, dx,
                                              N, Kused);
}

// Round 12
// 176.335 us; speedup vs baseline: 6.3677x; 1.0060x over previous
//
#include <hip/hip_runtime.h>

#define BATCH 8
#define NN 10000      // nodes per graph (N)
#define STB 512       // scatter block size (8 waves; 4 blocks/CU by LDS)

typedef _Float16 h2 __attribute__((ext_vector_type(2)));

// Packed 2xf16 LDS atomic add (ds_pk_add_f16): one atomic covers TWO batches.
__device__ __forceinline__ void lds_pk_add(h2* p, h2 v) {
    __builtin_amdgcn_ds_atomic_fadd_v2f16(
        (__attribute__((address_space(3))) h2*)p, v);
}

// prep: fx2[bp*N + t] = { tanh(values[2bp*N+t]), tanh(values[(2bp+1)*N+t]) }
__global__ __launch_bounds__(256) void prep_kernel(
        const float* __restrict__ values, h2* __restrict__ fx2, int N)
{
    int i = blockIdx.x * 256 + threadIdx.x;
    if (i >= 4 * N) return;
    int bp = i / N, t = i - bp * N;
    float a = values[(long)(2 * bp) * N + t];
    float b = values[(long)(2 * bp + 1) * N + t];
    h2 f = { (_Float16)tanhf(a), (_Float16)tanhf(b) };
    fx2[i] = f;
}

// Scatter: block (chunk k, batch-pair bp). Gather g2[bp*N + gi] (4B global,
// L1/L2-resident, VMEM pipe); pk-atomic into h2 LDS accumulator (DS pipe
// carries ONLY atomics). 8 edges per iteration for deep MLP.
__global__ __launch_bounds__(STB, 8) void scatter_kernel(
        const h2* __restrict__ g2,       // [4*N] packed gather values
        const float* __restrict__ w,     // [E]
        const int* __restrict__ idx,     // [2,E]
        h2* __restrict__ partial,
        int E, int N, int chunk, long goff, long soff)
{
    __shared__ alignas(16) h2 acc2[NN];
    const int k = blockIdx.x, bp = blockIdx.y;
    const h2* __restrict__ gb = g2 + (long)bp * N;

    int n4 = N >> 2;                       // N % 4 == 0
    int4* az = (int4*)acc2;
    for (int i = threadIdx.x; i < n4; i += STB) az[i] = make_int4(0, 0, 0, 0);
    __syncthreads();

    long e0 = (long)k * chunk, e1 = e0 + chunk;
    if (e0 > E) e0 = E;
    if (e1 > E) e1 = E;
    long n = e1 - e0;
    long nv8 = n >> 3;                     // 8-edge groups
    const int4*   g4p = (const int4*)(idx + goff + e0);
    const int4*   s4p = (const int4*)(idx + soff + e0);
    const float4* w4p = (const float4*)(w + e0);

    for (long v = threadIdx.x; v < nv8; v += STB) {
        int4 giA = g4p[2 * v], giB = g4p[2 * v + 1];
        int4 siA = s4p[2 * v], siB = s4p[2 * v + 1];
        float4 wvA = w4p[2 * v], wvB = w4p[2 * v + 1];
        // 8 independent VMEM gathers in flight
        h2 fA0 = gb[giA.x], fA1 = gb[giA.y], fA2 = gb[giA.z], fA3 = gb[giA.w];
        h2 fB0 = gb[giB.x], fB1 = gb[giB.y], fB2 = gb[giB.z], fB3 = gb[giB.w];
        h2 wA0 = { (_Float16)wvA.x, (_Float16)wvA.x };
        h2 wA1 = { (_Float16)wvA.y, (_Float16)wvA.y };
        h2 wA2 = { (_Float16)wvA.z, (_Float16)wvA.z };
        h2 wA3 = { (_Float16)wvA.w, (_Float16)wvA.w };
        h2 wB0 = { (_Float16)wvB.x, (_Float16)wvB.x };
        h2 wB1 = { (_Float16)wvB.y, (_Float16)wvB.y };
        h2 wB2 = { (_Float16)wvB.z, (_Float16)wvB.z };
        h2 wB3 = { (_Float16)wvB.w, (_Float16)wvB.w };
        lds_pk_add(&acc2[siA.x], wA0 * fA0);
        lds_pk_add(&acc2[siA.y], wA1 * fA1);
        lds_pk_add(&acc2[siA.z], wA2 * fA2);
        lds_pk_add(&acc2[siA.w], wA3 * fA3);
        lds_pk_add(&acc2[siB.x], wB0 * fB0);
        lds_pk_add(&acc2[siB.y], wB1 * fB1);
        lds_pk_add(&acc2[siB.z], wB2 * fB2);
        lds_pk_add(&acc2[siB.w], wB3 * fB3);
    }
    // tail: remaining edges (scalar)
    for (long e = (nv8 << 3) + threadIdx.x; e < n; e += STB) {
        int gi = idx[goff + e0 + e], si = idx[soff + e0 + e];
        _Float16 wf = (_Float16)w[e0 + e];
        h2 wb = { wf, wf };
        lds_pk_add(&acc2[si], wb * gb[gi]);
    }
    __syncthreads();

    int4* pz = (int4*)(partial + ((long)k * 4 + bp) * N);
    for (int i = threadIdx.x; i < n4; i += STB) pz[i] = az[i];
}

// ---------------- reduce 1: pred, err, err2 ----------------
// 512 thr: 64 lanes (4 consecutive t via int4) x 8 k-groups; fp32 tree.
__global__ __launch_bounds__(512) void reduce1_kernel(
        const h2* __restrict__ partial,
        const float* __restrict__ values,
        float* __restrict__ pred, float* __restrict__ err,
        h2* __restrict__ err2, int N, int K)
{
    __shared__ float2 sm[8][64][4];
    const int l = threadIdx.x & 63, g = threadIdx.x >> 6;
    const int bp = blockIdx.y;
    const int t = blockIdx.x * 256 + l * 4;
    float2 a0 = {0.f,0.f}, a1 = {0.f,0.f}, a2 = {0.f,0.f}, a3 = {0.f,0.f};
    const bool ok = (t + 3) < N;
    if (ok) {
        for (int kk = g; kk < K; kk += 8) {
            int4 v = *(const int4*)(partial + (long)(kk * 4 + bp) * N + t);
            h2* hp = (h2*)&v;
            a0.x += (float)hp[0].x; a0.y += (float)hp[0].y;
            a1.x += (float)hp[1].x; a1.y += (float)hp[1].y;
            a2.x += (float)hp[2].x; a2.y += (float)hp[2].y;
            a3.x += (float)hp[3].x; a3.y += (float)hp[3].y;
        }
    }
    sm[g][l][0] = a0; sm[g][l][1] = a1; sm[g][l][2] = a2; sm[g][l][3] = a3;
    __syncthreads();
    if (g == 0 && ok) {
#pragma unroll
        for (int r = 1; r < 8; ++r) {
            a0.x += sm[r][l][0].x; a0.y += sm[r][l][0].y;
            a1.x += sm[r][l][1].x; a1.y += sm[r][l][1].y;
            a2.x += sm[r][l][2].x; a2.y += sm[r][l][2].y;
            a3.x += sm[r][l][3].x; a3.y += sm[r][l][3].y;
        }
        long j0 = (long)(2 * bp) * N + t, j1 = j0 + N;
        float4 p0 = { a0.x, a1.x, a2.x, a3.x };
        float4 p1 = { a0.y, a1.y, a2.y, a3.y };
        float4 v0 = *(const float4*)(values + j0);
        float4 v1 = *(const float4*)(values + j1);
        float4 e0 = { v0.x - p0.x, v0.y - p0.y, v0.z - p0.z, v0.w - p0.w };
        float4 e1 = { v1.x - p1.x, v1.y - p1.y, v1.z - p1.z, v1.w - p1.w };
        *(float4*)(pred + j0) = p0;
        *(float4*)(pred + j1) = p1;
        *(float4*)(err + j0) = e0;
        *(float4*)(err + j1) = e1;
        h2 pk[4] = { { (_Float16)e0.x, (_Float16)e1.x },
                     { (_Float16)e0.y, (_Float16)e1.y },
                     { (_Float16)e0.z, (_Float16)e1.z },
                     { (_Float16)e0.w, (_Float16)e1.w } };
        *(int4*)(err2 + (long)bp * N + t) = *(int4*)pk;
    }
}

// ---------------- reduce 2: dx = err - (1 - tanh^2(x)) * aggr ----------------
__global__ __launch_bounds__(512) void reduce2_kernel(
        const h2* __restrict__ partial,
        const float* __restrict__ values,
        const float* __restrict__ err,
        float* __restrict__ dx, int N, int K)
{
    __shared__ float2 sm[8][64][4];
    const int l = threadIdx.x & 63, g = threadIdx.x >> 6;
    const int bp = blockIdx.y;
    const int t = blockIdx.x * 256 + l * 4;
    float2 a0 = {0.f,0.f}, a1 = {0.f,0.f}, a2 = {0.f,0.f}, a3 = {0.f,0.f};
    const bool ok = (t + 3) < N;
    if (ok) {
        for (int kk = g; kk < K; kk += 8) {
            int4 v = *(const int4*)(partial + (long)(kk * 4 + bp) * N + t);
            h2* hp = (h2*)&v;
            a0.x += (float)hp[0].x; a0.y += (float)hp[0].y;
            a1.x += (float)hp[1].x; a1.y += (float)hp[1].y;
            a2.x += (float)hp[2].x; a2.y += (float)hp[2].y;
            a3.x += (float)hp[3].x; a3.y += (float)hp[3].y;
        }
    }
    sm[g][l][0] = a0; sm[g][l][1] = a1; sm[g][l][2] = a2; sm[g][l][3] = a3;
    __syncthreads();
    if (g == 0 && ok) {
#pragma unroll
        for (int r = 1; r < 8; ++r) {
            a0.x += sm[r][l][0].x; a0.y += sm[r][l][0].y;
            a1.x += sm[r][l][1].x; a1.y += sm[r][l][1].y;
            a2.x += sm[r][l][2].x; a2.y += sm[r][l][2].y;
            a3.x += sm[r][l][3].x; a3.y += sm[r][l][3].y;
        }
        long j0 = (long)(2 * bp) * N + t, j1 = j0 + N;
        float4 g0 = { a0.x, a1.x, a2.x, a3.x };
        float4 g1 = { a0.y, a1.y, a2.y, a3.y };
        float4 v0 = *(const float4*)(values + j0);
        float4 v1 = *(const float4*)(values + j1);
        float4 e0 = *(const float4*)(err + j0);
        float4 e1 = *(const float4*)(err + j1);
        float4 d0, d1;
        float f;
        f = tanhf(v0.x); d0.x = e0.x - (1.0f - f * f) * g0.x;
        f = tanhf(v0.y); d0.y = e0.y - (1.0f - f * f) * g0.y;
        f = tanhf(v0.z); d0.z = e0.z - (1.0f - f * f) * g0.z;
        f = tanhf(v0.w); d0.w = e0.w - (1.0f - f * f) * g0.w;
        f = tanhf(v1.x); d1.x = e1.x - (1.0f - f * f) * g1.x;
        f = tanhf(v1.y); d1.y = e1.y - (1.0f - f * f) * g1.y;
        f = tanhf(v1.z); d1.z = e1.z - (1.0f - f * f) * g1.z;
        f = tanhf(v1.w); d1.w = e1.w - (1.0f - f * f) * g1.w;
        *(float4*)(dx + j0) = d0;
        *(float4*)(dx + j1) = d1;
    }
}

extern "C" void kernel_launch(void* const* d_in, const int* in_sizes, int n_in,
                              void* d_out, int out_size, void* d_ws, size_t ws_size,
                              hipStream_t stream) {
    const float* values  = (const float*)d_in[0];   // [B*N]
    const float* weights = (const float*)d_in[1];   // [E]
    const int*   edge_ix = (const int*)d_in[2];     // [2, E]

    const int BN = in_sizes[0];        // 80000
    const int E  = in_sizes[1];        // 2,000,000
    const int N  = BN / BATCH;         // 10000

    float* out  = (float*)d_out;       // [3, B*N]
    float* pred = out;
    float* err  = out + BN;
    float* dx   = out + 2 * BN;

    // workspace: fx2 [4N] h2 | err2 [4N] h2 | partial [K*4][N] h2
    auto align16 = [](size_t x) { return (x + 15) & ~(size_t)15; };
    char* ws = (char*)d_ws;
    h2* fx2 = (h2*)ws;
    size_t off = align16((size_t)4 * N * sizeof(h2));
    h2* err2 = (h2*)(ws + off);
    off += align16((size_t)4 * N * sizeof(h2));
    int K = 128;
    while (K > 16 && off + (size_t)K * 4 * N * sizeof(h2) > ws_size) K >>= 1;
    h2* partial = (h2*)(ws + off);

    int chunk = (((E + K - 1) / K) + 7) & ~7;   // multiple of 8
    int Kused = (E + chunk - 1) / chunk;

    dim3 sgrid(Kused, 4);                 // 4 batch-pairs
    dim3 rgrid((N + 255) / 256, 4);       // 512-thread reduce blocks

    prep_kernel<<<(4 * N + 255) / 256, 256, 0, stream>>>(values, fx2, N);
    scatter_kernel<<<sgrid, STB, 0, stream>>>(fx2, weights, edge_ix, partial,
                                              E, N, chunk, 0L, (long)E);
    reduce1_kernel<<<rgrid, 512, 0, stream>>>(partial, values, pred, err,
                                              err2, N, Kused);
    scatter_kernel<<<sgrid, STB, 0, stream>>>(err2, weights, edge_ix, partial,
                                              E, N, chunk, (long)E, 0L);
    reduce2_kernel<<<rgrid, 512, 0, stream>>>(partial, values, err, dx,
                                              N, Kused);
}